// Round 6
// baseline (302.693 us; speedup 1.0000x reference)
//
#include <hip/hip_runtime.h>

#define N_BLOCKS 12
#define D 256
#define BATCH 8192

typedef __attribute__((ext_vector_type(8))) short bf16x8;    // 8 bf16 = 4 VGPRs
typedef __attribute__((ext_vector_type(16))) float f32x16;   // 32x32 MFMA acc

// fp32 -> bf16 round-to-nearest-even (bit trick; inputs are finite)
__device__ __forceinline__ unsigned short f2bf(float f) {
  unsigned int u = __float_as_uint(f);
  u += 0x7fffu + ((u >> 16) & 1u);
  return (unsigned short)(u >> 16);
}

__device__ __forceinline__ unsigned int pk2(float a, float b) {
  return (unsigned)f2bf(a) | ((unsigned)f2bf(b) << 16);
}

// async global->LDS, 16B per lane. LDS dest = wave-uniform base + lane*16.
__device__ __forceinline__ void gld16(const unsigned short* g, unsigned short* l) {
  __builtin_amdgcn_global_load_lds(
      (const __attribute__((address_space(1))) unsigned int*)g,
      (__attribute__((address_space(3))) unsigned int*)l,
      16, 0, 0);
}

// ---- Pass 1: W[k][i][o] fp32 -> Wt[k][o][i] bf16, vectorized transpose ----
// Old version did 4 scalar 2B global stores/thread. New: 64x64 tiles,
// float4 loads, 16B stores. Grid 768 = 48 k x 16 tiles. LDS [o][i] so the
// store phase reads 16B vectors.
__global__ void cvt_w(const float* __restrict__ W, unsigned short* __restrict__ Wt) {
  __shared__ unsigned short T[64][72];   // [o][i], +8 pad
  const int b  = blockIdx.x;
  const int k  = b >> 4;
  const int ti = (b >> 2) & 3;           // i-tile
  const int tj = b & 3;                  // o-tile
  const float* Wk = W + (long long)k * D * D;
  unsigned short* Wtk = Wt + (long long)k * D * D;
  const int t = threadIdx.x;

  // load: thread reads float4 along o; write transposed into T[o][i] (scalar)
  #pragma unroll
  for (int p = 0; p < 4; ++p) {
    const int il = (t >> 4) + p * 16;
    const int o4 = (t & 15) * 4;
    const float4 v = *(const float4*)(Wk + (ti * 64 + il) * D + tj * 64 + o4);
    T[o4 + 0][il] = f2bf(v.x);
    T[o4 + 1][il] = f2bf(v.y);
    T[o4 + 2][il] = f2bf(v.z);
    T[o4 + 3][il] = f2bf(v.w);
  }
  __syncthreads();

  // store: 16B of 8 consecutive i at fixed o (contiguous in Wt)
  #pragma unroll
  for (int q = 0; q < 2; ++q) {
    const int ol = t >> 2;
    const int i8 = (t & 3) * 8 + q * 32;
    *(uint4*)(Wtk + (tj * 64 + ol) * D + ti * 64 + i8) = *(const uint4*)(&T[ol][i8]);
  }
}

// ------------- Pass 2: block-sparse GEMM, BM=256, BN=128, BK=32 ------------
// R5 post-mortem: bs_gemm ~77us with all pipes <30% AND total = bs_gemm +
// ~173us across all rounds -> the cvt passes dominate end-to-end time.
// This version DELETES cvt_x: A is staged from fp32 X with in-register
// f2bf conversion (reg-staged, T14-style), eliminating a full 144MB pass.
//  - Per tile: [barrier] [B gld16 kt+1 -> slot^1] [12 frag ds_reads slot]
//    [lgkm0] [16 MFMA] [A convert+ds_write kt+1 -> slot^1 (auto-vmcnt
//    retires A loads, B stays flying)] [issue A kt+2, sched-pinned]
//    [vmcnt(8): retire B kt+1, leave A kt+2 flying] [lgkm0].
//    ONE barrier/tile; vmcnt never 0 in steady state.
//  - A LDS layout identical to R5 (chunk c of row r at c^((r>>1)&3)),
//    applied on the ds_write address; fragment reader unchanged (proven).
//  - B path unchanged from R5 (gld16 + inverse-swizzled global source).
//  - 2 LDS slots x 24KB = 48KB; launch_bounds(256,2) -> VGPR cap 256
//    (acc 128 + rA 32 + frags 48 + addr fits, no spill).
//  - f2bf order identical to cvt_x+bf16-MFMA -> bit-identical output.
__launch_bounds__(256, 2)
__global__ void bs_gemm(const float* __restrict__ X,
                        const unsigned short* __restrict__ Wt,
                        const float* __restrict__ bias,
                        const int* __restrict__ i_idx,
                        const int* __restrict__ j_idx,
                        int nact,
                        float* __restrict__ Y) {
  __shared__ unsigned short lds[2 * 12288];   // 2 slots x 24KB = 48KB

  // XCD-aware decode (dispatch round-robin heuristic), as R5
  const int bid = blockIdx.x;
  const int x   = bid & 7;             // XCD
  const int loc = bid >> 3;            // 0..95
  const int bm  = x * 4 + (loc & 3);   // this XCD's 4-wide bm slice (256-row)
  const int pp  = loc >> 2;            // 0..23
  const int i   = pp >> 1;             // output row
  const int bn  = pp & 1;              // 128-col half

  // collect active blocks feeding output row i (pattern gives exactly 4)
  int ks0 = 0, ks1 = 0, ks2 = 0, ks3 = 0, js0 = 0, js1 = 0, js2 = 0, js3 = 0, nk = 0;
  for (int k = 0; k < nact; ++k) {
    if (i_idx[k] == i) {
      const int j = j_idx[k];
      if      (nk == 0) { ks0 = k; js0 = j; }
      else if (nk == 1) { ks1 = k; js1 = j; }
      else if (nk == 2) { ks2 = k; js2 = j; }
      else              { ks3 = k; js3 = j; }
      ++nk;
    }
  }
#define JS(t) ((t) == 0 ? js0 : (t) == 1 ? js1 : (t) == 2 ? js2 : js3)
#define KS(t) ((t) == 0 ? ks0 : (t) == 1 ? ks1 : (t) == 2 ? ks2 : ks3)

  const int tid  = threadIdx.x;
  const int wave = tid >> 6;
  const int lane = tid & 63;
  const int wm   = wave >> 1;            // 0..1 (m half, 128 rows)
  const int wn   = wave & 1;             // 0..1 (n half, 64 cols)
  const int l31  = lane & 31;
  const int lh   = lane >> 5;            // k-half within frag

  // A staging: thread owns rows srow+64*sb, logical 8-float chunk scnk.
  // Swizzled LDS position cpos = scnk ^ ((row>>1)&3); (row>>1)&3 ==
  // (tid>>3)&3 for all 4 sub-blocks (64-row strides keep bits [2:1]).
  const int srow = tid >> 2;             // 0..63
  const int scnk = tid & 3;
  const int cpos = scnk ^ ((tid >> 3) & 3);

  // B staging source (inverse-swizzled global chunk), as R5
  const int g_off = (tid >> 2) * D + (((tid & 3) ^ ((tid >> 3) & 3)) * 8);

  // fragment read offsets (bytes in slot), as R5; slot stride 24576 B
  const int sw   = (l31 >> 1) & 3;
  const int cko0 = ((0 + lh) ^ sw) << 4;
  const int cko1 = ((2 + lh) ^ sw) << 4;
  const int aBase = (wm * 128 + l31) * 64;
  const int bBase = 16384 + (wn * 64 + l31) * 64;

  float4 rA[8];

  auto A_ISSUE = [&](int st) {
    const int t  = st >> 3;
    const int kk = st & 7;
    const float* base = X + ((long long)JS(t) * BATCH + bm * 256) * D
                          + kk * 32 + scnk * 8;
    #pragma unroll
    for (int sb = 0; sb < 4; ++sb) {
      const float4* p = (const float4*)(base + (long long)(srow + 64 * sb) * D);
      rA[2 * sb]     = p[0];
      rA[2 * sb + 1] = p[1];
    }
  };
  auto A_WRITE = [&](int st) {
    unsigned short* sl = lds + (st & 1) * 12288;
    #pragma unroll
    for (int sb = 0; sb < 4; ++sb) {
      const float4 a = rA[2 * sb], b = rA[2 * sb + 1];
      uint4 v;
      v.x = pk2(a.x, a.y);  v.y = pk2(a.z, a.w);
      v.z = pk2(b.x, b.y);  v.w = pk2(b.z, b.w);
      *(uint4*)(sl + (srow + 64 * sb) * 32 + cpos * 8) = v;
    }
  };
  auto STAGE_B = [&](int st) {
    const int t  = st >> 3;
    const int kk = st & 7;
    unsigned short* sl = lds + (st & 1) * 12288 + 8192;
    const unsigned short* Bs =
        Wt + ((long long)KS(t) * D + bn * 128) * D + kk * 32 + g_off;
    gld16(Bs,          sl + tid * 8);
    gld16(Bs + 64 * D, sl + 2048 + tid * 8);
  };

  f32x16 acc[4][2] = {};

  // prologue: tile 0 fully staged; A tile 1 in flight
  STAGE_B(0);
  A_ISSUE(0);
  __builtin_amdgcn_sched_barrier(0);
  A_WRITE(0);                            // auto-vmcnt drains A0 (and B0)
  __builtin_amdgcn_sched_barrier(0);
  A_ISSUE(1);
  __builtin_amdgcn_sched_barrier(0);
  asm volatile("s_waitcnt lgkmcnt(0)" ::: "memory");

  #pragma unroll
  for (int kt = 0; kt < 32; ++kt) {
    __builtin_amdgcn_s_barrier();        // publishes slot kt&1 (tile kt)
    __builtin_amdgcn_sched_barrier(0);

    if (kt < 31) STAGE_B(kt + 1);        // 2 gld16 -> slot^1, max latency

    const char* sb = (const char*)lds + (kt & 1) * 24576;
    bf16x8 aF[2][4], bF[2][2];
    #pragma unroll
    for (int mf = 0; mf < 4; ++mf) {
      aF[0][mf] = *(const bf16x8*)(sb + aBase + mf * 2048 + cko0);
      aF[1][mf] = *(const bf16x8*)(sb + aBase + mf * 2048 + cko1);
    }
    #pragma unroll
    for (int nf = 0; nf < 2; ++nf) {
      bF[0][nf] = *(const bf16x8*)(sb + bBase + nf * 2048 + cko0);
      bF[1][nf] = *(const bf16x8*)(sb + bBase + nf * 2048 + cko1);
    }

    asm volatile("s_waitcnt lgkmcnt(0)" ::: "memory");
    __builtin_amdgcn_sched_barrier(0);   // rule #18: pin MFMA below the wait

    __builtin_amdgcn_s_setprio(1);
    #pragma unroll
    for (int kh = 0; kh < 2; ++kh)
      #pragma unroll
      for (int mf = 0; mf < 4; ++mf)
        #pragma unroll
        for (int nf = 0; nf < 2; ++nf)
          acc[mf][nf] = __builtin_amdgcn_mfma_f32_32x32x16_bf16(
              aF[kh][mf], bF[kh][nf], acc[mf][nf], 0, 0, 0);
    __builtin_amdgcn_s_setprio(0);

    if (kt < 31) A_WRITE(kt + 1);        // auto-vmcnt retires A(kt+1) only
    __builtin_amdgcn_sched_barrier(0);
    if (kt < 30) A_ISSUE(kt + 2);        // pinned: stays above the vmcnt
    __builtin_amdgcn_sched_barrier(0);

    // retire B(kt+1) before the next barrier; A(kt+2) keeps flying
    if (kt < 30)       asm volatile("s_waitcnt vmcnt(8)" ::: "memory");
    else if (kt == 30) asm volatile("s_waitcnt vmcnt(0)" ::: "memory");
    if (kt < 31) asm volatile("s_waitcnt lgkmcnt(0)" ::: "memory");
  }

  // epilogue: 32x32 C/D layout col=lane&31, row=(reg&3)+8*(reg>>2)+4*(lane>>5)
  float* Yb = Y + (long long)i * BATCH * D;
  const int m0 = bm * 256 + wm * 128;
  const int n0 = bn * 128 + wn * 64 + l31;
  float bsum[2];
  #pragma unroll
  for (int nf = 0; nf < 2; ++nf) {
    float s = 0.f;
    for (int t = 0; t < nk; ++t) s += bias[KS(t) * D + n0 + nf * 32];
    bsum[nf] = s;
  }
  #pragma unroll
  for (int nf = 0; nf < 2; ++nf)
    #pragma unroll
    for (int mf = 0; mf < 4; ++mf)
      #pragma unroll
      for (int rg = 0; rg < 16; ++rg) {
        const int row = (rg & 3) + 8 * (rg >> 2) + 4 * lh;
        Yb[(long long)(m0 + mf * 32 + row) * D + (n0 + nf * 32)] =
            acc[mf][nf][rg] + bsum[nf];
      }
#undef JS
#undef KS
}

extern "C" void kernel_launch(void* const* d_in, const int* in_sizes, int n_in,
                              void* d_out, int out_size, void* d_ws, size_t ws_size,
                              hipStream_t stream) {
  const float* X = (const float*)d_in[0];
  const float* W = (const float*)d_in[1];
  const float* b = (const float*)d_in[2];
  const int* i_idx = (const int*)d_in[3];
  const int* j_idx = (const int*)d_in[4];
  float* Y = (float*)d_out;
  const int nact = in_sizes[3];   // 48

  // workspace: Wt (6 MB bf16, transposed) only — cvt_x eliminated
  unsigned short* Wt = (unsigned short*)d_ws;

  cvt_w<<<768, 256, 0, stream>>>(W, Wt);
  // grid: 8 XCD x (12 i x 2 bn x 4 bm) = 768 = 3 even rounds of 256 CUs
  bs_gemm<<<768, 256, 0, stream>>>(X, Wt, b, i_idx, j_idx, nact, Y);
}